// Round 1
// baseline (253.085 us; speedup 1.0000x reference)
//
#include <hip/hip_runtime.h>

#define IMG 256
#define TPX 16                // tile pixel width (16x16 px tiles)
#define TPB 256               // tiles per batch image (16*16)
#define RSPLIT 16             // waves per tile in raster
#define SPLIT 4               // fallback: row-block waves per face
#define DELTA 1e-3f           // conservative margin >> fp32 rounding (~2e-6)

// Fused: zero output image, zero bin counters/flags, project vertices to NDC.
// Projection replicates numpy float32 op order exactly (no fma contraction).
__global__ void init_kernel(const float* __restrict__ verts,
                            const float* __restrict__ cams,
                            float4* __restrict__ out4, int n4,
                            float2* __restrict__ ndc, int BV, int V,
                            int* __restrict__ meta, int nmeta) {
    int i = blockIdx.x * blockDim.x + threadIdx.x;
    if (i < n4) out4[i] = make_float4(0.f, 0.f, 0.f, 0.f);
    if (i < nmeta) meta[i] = 0;
    if (i < BV) {
        int b = i / V;
        float f  = __fadd_rn(__fmul_rn(1.0f, cams[b * 3 + 0]), 0.0f);
        float cx = cams[b * 3 + 1];
        float cy = cams[b * 3 + 2];
        float image_size = __fmul_rn(cams[1], 2.0f);  // cam[0,1] * 2.0
        float x = verts[3 * i + 0];
        float y = verts[3 * i + 1];
        float z = __fadd_rn(verts[3 * i + 2], 0.0f);
        float px = __fadd_rn(__fdiv_rn(__fmul_rn(f, x), z), cx);
        float py = __fadd_rn(__fdiv_rn(__fmul_rn(f, y), z), cy);
        float nx = __fsub_rn(__fmul_rn(__fdiv_rn(px, image_size), 2.0f), 1.0f);
        float ny = __fsub_rn(__fmul_rn(__fdiv_rn(py, image_size), 2.0f), 1.0f);
        ndc[i] = make_float2(nx, ny);
    }
}

// One wave per face; lanes parallel over the face's bbox tiles.
// Per (face,tile), conservative interval test of the 3 edge functions over the
// tile's pixel-center rectangle with margin DELTA:
//   all edges >= +DELTA (or <= -DELTA) at corners -> face dominates tile (flag)
//   provably outside (mixed strict signs)        -> skip
//   else                                          -> append to tile face list
// DELTA=1e-3 dwarfs the ~2e-6 rounding bound of both this corner eval and the
// reference's per-pixel eval, so classification is consistent with reference.
__global__ __launch_bounds__(256) void bin_kernel(
        const float2* __restrict__ ndc, const int* __restrict__ faces,
        int* __restrict__ cnt, int* __restrict__ dom, int* __restrict__ list,
        int CAP, int B, int V, int F) {
    int gid  = blockIdx.x * blockDim.x + threadIdx.x;
    int wave = gid >> 6;
    int lane = gid & 63;
    if (wave >= B * F) return;
    int b   = wave / F;
    int fid = wave - b * F;
    const int* fp = faces + (size_t)wave * 3;
    const float2* nb = ndc + (size_t)b * V;
    float2 v0 = nb[fp[0]];
    float2 v1 = nb[fp[1]];
    float2 v2 = nb[fp[2]];

    float area = __fsub_rn(
        __fmul_rn(__fsub_rn(v1.x, v0.x), __fsub_rn(v2.y, v0.y)),
        __fmul_rn(__fsub_rn(v1.y, v0.y), __fsub_rn(v2.x, v0.x)));
    if (!(fabsf(area) > 1e-12f)) return;

    float xmn = fminf(v0.x, fminf(v1.x, v2.x));
    float xmx = fmaxf(v0.x, fmaxf(v1.x, v2.x));
    float ymn = fminf(v0.y, fminf(v1.y, v2.y));
    float ymx = fmaxf(v0.y, fmaxf(v1.y, v2.y));
    int ix0 = max(0,       (int)floorf(xmn * 128.0f + 127.5f) - 1);
    int ix1 = min(IMG - 1, (int)ceilf (xmx * 128.0f + 127.5f) + 1);
    int iy0 = max(0,       (int)floorf(ymn * 128.0f + 127.5f) - 1);
    int iy1 = min(IMG - 1, (int)ceilf (ymx * 128.0f + 127.5f) + 1);
    if (ix1 < ix0 || iy1 < iy0) return;

    int tx0 = ix0 >> 4, tx1 = ix1 >> 4;
    int ty0 = iy0 >> 4, ty1 = iy1 >> 4;
    int tw = tx1 - tx0 + 1;
    int nt = tw * (ty1 - ty0 + 1);

    float e0x = __fsub_rn(v2.x, v1.x), e0y = __fsub_rn(v2.y, v1.y);
    float e1x = __fsub_rn(v0.x, v2.x), e1y = __fsub_rn(v0.y, v2.y);
    float e2x = __fsub_rn(v1.x, v0.x), e2y = __fsub_rn(v1.y, v0.y);

    const float EXT = 0.1171875f;  // 30/256: span between first/last pixel centers

    for (int t = lane; t < nt; t += 64) {
        int trow = t / tw;
        int ttx  = tx0 + (t - trow * tw);
        int tty  = ty0 + trow;
        float cx0 = (float)(2 * (ttx << 4) + 1) * 0.00390625f - 1.0f;
        float cy0 = (float)(2 * (tty << 4) + 1) * 0.00390625f - 1.0f;
        // edge w(px,py) = (px-ax)*ey - (py-ay)*ex; affine -> corner extremes
        float w0 = (cx0 - v1.x) * e0y - (cy0 - v1.y) * e0x;
        float w1 = (cx0 - v2.x) * e1y - (cy0 - v2.y) * e1x;
        float w2 = (cx0 - v0.x) * e2y - (cy0 - v0.y) * e2x;
        float ax0 = EXT * e0y, ay0 = -EXT * e0x;
        float ax1 = EXT * e1y, ay1 = -EXT * e1x;
        float ax2 = EXT * e2y, ay2 = -EXT * e2x;
        float mn0 = w0 + fminf(ax0, 0.f) + fminf(ay0, 0.f);
        float mx0 = w0 + fmaxf(ax0, 0.f) + fmaxf(ay0, 0.f);
        float mn1 = w1 + fminf(ax1, 0.f) + fminf(ay1, 0.f);
        float mx1 = w1 + fmaxf(ax1, 0.f) + fmaxf(ay1, 0.f);
        float mn2 = w2 + fminf(ax2, 0.f) + fminf(ay2, 0.f);
        float mx2 = w2 + fmaxf(ax2, 0.f) + fmaxf(ay2, 0.f);

        int tid_ = (b << 8) + (tty << 4) + ttx;
        bool posIn = fminf(mn0, fminf(mn1, mn2)) >  DELTA;
        bool negIn = fmaxf(mx0, fmaxf(mx1, mx2)) < -DELTA;
        if (posIn || negIn) {
            dom[tid_] = 1;                 // benign race: all writers store 1
        } else {
            bool outz = (fminf(mx0, fminf(mx1, mx2)) < -DELTA) &&
                        (fmaxf(mn0, fmaxf(mn1, mn2)) >  DELTA);
            if (!outz) {
                int s = atomicAdd(&cnt[tid_], 1);   // s < F == CAP always
                list[(size_t)tid_ * CAP + s] = fid;
            }
        }
    }
}

// RSPLIT waves per tile. Dominated tiles: one wave stores 256 ones, no math.
// Others: strided walk of the tile's face list, bit-exact edge tests, per-wave
// __all early exit. Lane covers 1 column x 4 rows (rows dy, dy+4, dy+8, dy+12).
__global__ __launch_bounds__(256) void raster_tiles(
        const float2* __restrict__ ndc, const int* __restrict__ faces,
        const int* __restrict__ cnt, const int* __restrict__ dom,
        const int* __restrict__ list, int CAP, float* __restrict__ out,
        int B, int V, int F) {
    int gid  = blockIdx.x * blockDim.x + threadIdx.x;
    int wave = gid >> 6;
    int lane = gid & 63;
    int tile = wave >> 4;            // / RSPLIT
    int sub  = wave & (RSPLIT - 1);
    if (tile >= B * TPB) return;
    int b = tile >> 8;
    int t = tile & 255;
    int tx0 = (t & 15) << 4;
    int ty0 = (t >> 4) << 4;
    int dx = lane & 15;
    int dy = lane >> 4;              // 0..3
    int X  = tx0 + dx;
    float* outb = out + ((size_t)b << 16);

    if (dom[tile]) {
        if (sub == 0) {
            #pragma unroll
            for (int k = 0; k < 4; ++k)
                outb[(ty0 + dy + 4 * k) * IMG + X] = 1.0f;
        }
        return;
    }
    int n = cnt[tile];
    if (sub >= n) return;

    const int* lp = list + (size_t)tile * CAP;
    const int* fb = faces + (size_t)b * F * 3;
    const float2* nb = ndc + (size_t)b * V;

    float px = (float)(2 * X + 1) * 0.00390625f - 1.0f;
    int y0 = ty0 + dy;
    float pyA = (float)(2 * y0 + 1)        * 0.00390625f - 1.0f;
    float pyB = (float)(2 * (y0 + 4) + 1)  * 0.00390625f - 1.0f;
    float pyC = (float)(2 * (y0 + 8) + 1)  * 0.00390625f - 1.0f;
    float pyD = (float)(2 * (y0 + 12) + 1) * 0.00390625f - 1.0f;

    bool cA = false, cB = false, cC = false, cD = false;

    for (int i = sub; i < n; i += RSPLIT) {
        int fid = lp[i];
        const int* fp = fb + fid * 3;
        float2 v0 = nb[fp[0]];
        float2 v1 = nb[fp[1]];
        float2 v2 = nb[fp[2]];
        float e0x = __fsub_rn(v2.x, v1.x), e0y = __fsub_rn(v2.y, v1.y);
        float e1x = __fsub_rn(v0.x, v2.x), e1y = __fsub_rn(v0.y, v2.y);
        float e2x = __fsub_rn(v1.x, v0.x), e2y = __fsub_rn(v1.y, v0.y);
        // column terms (shared by the lane's 4 rows)
        float a0 = __fmul_rn(__fsub_rn(px, v1.x), e0y);
        float a1 = __fmul_rn(__fsub_rn(px, v2.x), e1y);
        float a2 = __fmul_rn(__fsub_rn(px, v0.x), e2y);
        #define ROWTEST(PY, C) { \
            float w0 = __fsub_rn(a0, __fmul_rn(__fsub_rn(PY, v1.y), e0x)); \
            float w1 = __fsub_rn(a1, __fmul_rn(__fsub_rn(PY, v2.y), e1x)); \
            float w2 = __fsub_rn(a2, __fmul_rn(__fsub_rn(PY, v0.y), e2x)); \
            float mn = fminf(w0, fminf(w1, w2)); \
            float mx = fmaxf(w0, fmaxf(w1, w2)); \
            C = C || ((mn >= 0.f) || (mx <= 0.f)); }
        ROWTEST(pyA, cA)
        ROWTEST(pyB, cB)
        ROWTEST(pyC, cC)
        ROWTEST(pyD, cD)
        #undef ROWTEST
        if (__all((int)(cA && cB && cC && cD))) break;
    }
    if (cA) outb[ y0       * IMG + X] = 1.0f;
    if (cB) outb[(y0 + 4)  * IMG + X] = 1.0f;
    if (cC) outb[(y0 + 8)  * IMG + X] = 1.0f;
    if (cD) outb[(y0 + 12) * IMG + X] = 1.0f;
}

// ---- Fallback (proven 66us face-parallel kernel) if workspace too small ----
__global__ __launch_bounds__(256) void raster_kernel(
        const float2* __restrict__ ndc, const int* __restrict__ faces,
        float* __restrict__ out, int B, int V, int F) {
    int gid  = blockIdx.x * blockDim.x + threadIdx.x;
    int wave = gid >> 6;
    int lane = gid & 63;
    int widx = wave >> 2;
    int sub  = wave & (SPLIT - 1);
    if (widx >= B * F) return;
    int b  = widx / F;
    const int* fp = faces + (size_t)widx * 3;
    const float2* nb = ndc + (size_t)b * V;
    float2 v0 = nb[fp[0]];
    float2 v1 = nb[fp[1]];
    float2 v2 = nb[fp[2]];
    float area = __fsub_rn(
        __fmul_rn(__fsub_rn(v1.x, v0.x), __fsub_rn(v2.y, v0.y)),
        __fmul_rn(__fsub_rn(v1.y, v0.y), __fsub_rn(v2.x, v0.x)));
    if (!(fabsf(area) > 1e-12f)) return;
    float xmn = fminf(v0.x, fminf(v1.x, v2.x));
    float xmx = fmaxf(v0.x, fmaxf(v1.x, v2.x));
    float ymn = fminf(v0.y, fminf(v1.y, v2.y));
    float ymx = fmaxf(v0.y, fmaxf(v1.y, v2.y));
    int ix0 = max(0,       (int)floorf(xmn * 128.0f + 127.5f) - 1);
    int ix1 = min(IMG - 1, (int)ceilf (xmx * 128.0f + 127.5f) + 1);
    int iy0 = max(0,       (int)floorf(ymn * 128.0f + 127.5f) - 1);
    int iy1 = min(IMG - 1, (int)ceilf (ymx * 128.0f + 127.5f) + 1);
    if (ix1 < ix0 || iy1 < iy0) return;
    int W = ix1 - ix0 + 1, H = iy1 - iy0 + 1;
    int tws = 6, bestIt = ((W + 63) >> 6) * H;
    int it;
    it = ((W + 31) >> 5) * ((H + 1) >> 1); if (it < bestIt) { bestIt = it; tws = 5; }
    it = ((W + 15) >> 4) * ((H + 3) >> 2); if (it < bestIt) { bestIt = it; tws = 4; }
    it = ((W + 7)  >> 3) * ((H + 7) >> 3); if (it < bestIt) { bestIt = it; tws = 3; }
    int TW = 1 << tws, TH = 64 >> tws;
    int dx = lane & (TW - 1), dy = lane >> tws;
    float e0x = __fsub_rn(v2.x, v1.x), e0y = __fsub_rn(v2.y, v1.y);
    float e1x = __fsub_rn(v0.x, v2.x), e1y = __fsub_rn(v0.y, v2.y);
    float e2x = __fsub_rn(v1.x, v0.x), e2y = __fsub_rn(v1.y, v0.y);
    float* outb = out + (size_t)b * IMG * IMG;
    float pxStep = (float)TW * 0.0078125f;
    for (int ty = iy0 + sub * TH; ty <= iy1; ty += SPLIT * TH) {
        int y = ty + dy;
        bool yok = (y <= iy1);
        float py = (float)(2 * y + 1) * 0.00390625f - 1.0f;
        float t0 = __fmul_rn(__fsub_rn(py, v1.y), e0x);
        float t1 = __fmul_rn(__fsub_rn(py, v2.y), e1x);
        float t2 = __fmul_rn(__fsub_rn(py, v0.y), e2x);
        float* p = outb + y * IMG + ix0 + dx;
        int x = ix0 + dx;
        float px = (float)(2 * x + 1) * 0.00390625f - 1.0f;
        for (int tx = ix0; tx <= ix1; tx += TW) {
            float w0 = __fsub_rn(__fmul_rn(__fsub_rn(px, v1.x), e0y), t0);
            float w1 = __fsub_rn(__fmul_rn(__fsub_rn(px, v2.x), e1y), t1);
            float w2 = __fsub_rn(__fmul_rn(__fsub_rn(px, v0.x), e2y), t2);
            float mn = fminf(w0, fminf(w1, w2));
            float mx = fmaxf(w0, fmaxf(w1, w2));
            bool inside = (mn >= 0.f) | (mx <= 0.f);
            if (inside & yok & (x <= ix1)) *p = 1.0f;
            px += pxStep;
            x  += TW;
            p  += TW;
        }
    }
}

extern "C" void kernel_launch(void* const* d_in, const int* in_sizes, int n_in,
                              void* d_out, int out_size, void* d_ws, size_t ws_size,
                              hipStream_t stream) {
    const float* verts = (const float*)d_in[0];
    const int*   faces = (const int*)d_in[1];
    const float* cams  = (const float*)d_in[2];
    float* out = (float*)d_out;

    int B = in_sizes[2] / 3;
    int V = in_sizes[0] / (3 * B);
    int F = in_sizes[1] / (3 * B);

    size_t ndcB  = (((size_t)B * V * sizeof(float2)) + 255) & ~(size_t)255;
    int ntiles   = B * TPB;
    size_t metaB = (((size_t)ntiles * 2 * sizeof(int)) + 255) & ~(size_t)255;
    int CAP      = F;                                 // always-safe capacity
    size_t listB = (size_t)ntiles * CAP * sizeof(int);
    int fast = (ws_size >= ndcB + metaB + listB) ? 1 : 0;

    float2* ndc = (float2*)d_ws;
    int* cnt  = (int*)((char*)d_ws + ndcB);
    int* dom  = cnt + ntiles;
    int* list = (int*)((char*)d_ws + ndcB + metaB);

    int n4 = out_size / 4;
    int nmeta = fast ? ntiles * 2 : 0;
    int initThreads = n4 > B * V ? n4 : B * V;
    if (nmeta > initThreads) initThreads = nmeta;
    hipLaunchKernelGGL(init_kernel, dim3((initThreads + 255) / 256), dim3(256), 0,
                       stream, verts, cams, (float4*)d_out, n4, ndc, B * V, V,
                       cnt, nmeta);

    if (fast) {
        long long bt = (long long)B * F * 64;
        hipLaunchKernelGGL(bin_kernel, dim3((int)((bt + 255) / 256)), dim3(256), 0,
                           stream, ndc, faces, cnt, dom, list, CAP, B, V, F);
        long long rt = (long long)ntiles * RSPLIT * 64;
        hipLaunchKernelGGL(raster_tiles, dim3((int)((rt + 255) / 256)), dim3(256), 0,
                           stream, ndc, faces, cnt, dom, list, CAP, out, B, V, F);
    } else {
        long long nthreads = (long long)B * F * SPLIT * 64;
        hipLaunchKernelGGL(raster_kernel, dim3((int)((nthreads + 255) / 256)), dim3(256),
                           0, stream, ndc, faces, out, B, V, F);
    }
}

// Round 2
// 93.893 us; speedup vs baseline: 2.6955x; 2.6955x over previous
//
#include <hip/hip_runtime.h>

#define IMG 256
#define CAP 768           // LDS partial-face list capacity (flush-chunked, can't overflow)
#define DELTA 1e-3f       // conservative margin >> fp32 rounding (~2e-6)
#define SPLIT 4           // fallback kernel: row-block waves per face

// 32B per-face record: projected verts + packed conservative pixel bbox.
struct __align__(16) FaceRec { float4 a; float4 b; };
// a = (v0x, v0y, v1x, v1y); b = (v2x, v2y, bbox_bits, 0)
// bbox_bits = ix0 | ix1<<8 | iy0<<16 | iy1<<24 (clamped to [0,255]);
// sentinel 0x00FF00FF (ix0=255, ix1=0) overlaps no tile -> face culled.

// One thread per (b,f): re-projects its 3 vertices (bit-identical numpy fp32
// op order; ~6x redundant vs per-vertex but removes a kernel + dependency),
// computes validity + conservative bbox, writes one coalesced 32B record.
__global__ void prep_kernel(const float* __restrict__ verts,
                            const int* __restrict__ faces,
                            const float* __restrict__ cams,
                            FaceRec* __restrict__ recs, int B, int V, int F) {
    int i = blockIdx.x * blockDim.x + threadIdx.x;
    if (i >= B * F) return;
    int b = i / F;
    const int* fp = faces + (size_t)i * 3;
    float f  = __fadd_rn(__fmul_rn(1.0f, cams[b * 3 + 0]), 0.0f);
    float cx = cams[b * 3 + 1];
    float cy = cams[b * 3 + 2];
    float image_size = __fmul_rn(cams[1], 2.0f);  // cam[0,1] * 2.0
    float vx[3], vy[3];
    #pragma unroll
    for (int k = 0; k < 3; ++k) {
        const float* vp = verts + ((size_t)b * V + fp[k]) * 3;
        float x = vp[0], y = vp[1];
        float z = __fadd_rn(vp[2], 0.0f);
        float px = __fadd_rn(__fdiv_rn(__fmul_rn(f, x), z), cx);
        float py = __fadd_rn(__fdiv_rn(__fmul_rn(f, y), z), cy);
        vx[k] = __fsub_rn(__fmul_rn(__fdiv_rn(px, image_size), 2.0f), 1.0f);
        vy[k] = __fsub_rn(__fmul_rn(__fdiv_rn(py, image_size), 2.0f), 1.0f);
    }
    float area = __fsub_rn(
        __fmul_rn(__fsub_rn(vx[1], vx[0]), __fsub_rn(vy[2], vy[0])),
        __fmul_rn(__fsub_rn(vy[1], vy[0]), __fsub_rn(vx[2], vx[0])));
    int bb = 0x00FF00FF;  // sentinel: never overlaps any tile
    if (fabsf(area) > 1e-12f) {   // NaN-safe: NaN -> false -> culled (== ref valid mask)
        float xmn = fminf(vx[0], fminf(vx[1], vx[2]));
        float xmx = fmaxf(vx[0], fmaxf(vx[1], vx[2]));
        float ymn = fminf(vy[0], fminf(vy[1], vy[2]));
        float ymx = fmaxf(vy[0], fmaxf(vy[1], vy[2]));
        int ix0 = max(0,       (int)floorf(xmn * 128.0f + 127.5f) - 1);
        int ix1 = min(IMG - 1, (int)ceilf (xmx * 128.0f + 127.5f) + 1);
        int iy0 = max(0,       (int)floorf(ymn * 128.0f + 127.5f) - 1);
        int iy1 = min(IMG - 1, (int)ceilf (ymx * 128.0f + 127.5f) + 1);
        if (ix0 <= ix1 && iy0 <= iy1)
            bb = ix0 | (ix1 << 8) | (iy0 << 16) | (iy1 << 24);
    }
    recs[i].a = make_float4(vx[0], vy[0], vx[1], vy[1]);
    recs[i].b = make_float4(vx[2], vy[2], __int_as_float(bb), 0.0f);
}

// One 256-thread block per 16x16 tile (1 thread = 1 pixel). Scans faces in
// coalesced 256-face chunks; classifies each (face,tile) with the proven
// DELTA-margin corner-interval test:
//   dominates -> whole tile covered, uniform break (no per-pixel work at all)
//   outside   -> drop
//   partial   -> append verts to LDS list; rastered per-pixel bit-exactly.
// List flushes when near CAP, so any list size is safe. Every pixel written
// exactly once unconditionally -> no output zeroing pass needed.
__global__ __launch_bounds__(256) void tile_kernel(
        const FaceRec* __restrict__ recs, float* __restrict__ out,
        int B, int F) {
    __shared__ float fl[CAP * 6];
    __shared__ int s_cnt, s_dom;
    int tile = blockIdx.x;
    int b = tile >> 8, t = tile & 255;
    int tx0 = (t & 15) << 4, ty0 = (t >> 4) << 4;
    int tid = threadIdx.x;
    if (tid == 0) { s_cnt = 0; s_dom = 0; }
    int X = tx0 + (tid & 15), Y = ty0 + (tid >> 4);
    // pixel centers (2k+1)/256 - 1, exactly representable in fp32
    float px = (float)(2 * X + 1) * 0.00390625f - 1.0f;
    float py = (float)(2 * Y + 1) * 0.00390625f - 1.0f;
    float cx0 = (float)(2 * tx0 + 1) * 0.00390625f - 1.0f;
    float cy0 = (float)(2 * ty0 + 1) * 0.00390625f - 1.0f;
    int txm = tx0 + 15, tym = ty0 + 15;
    const float EXT = 0.1171875f;  // 30/256: span of the tile's pixel centers
    const FaceRec* rb = recs + (size_t)b * F;
    bool covered = false;
    __syncthreads();

    for (int base = 0; base < F; base += 256) {
        int fid = base + tid;
        int cls = 0;
        float v0x, v0y, v1x, v1y, v2x, v2y;
        if (fid < F) {
            float4 ra = rb[fid].a;
            float4 rc = rb[fid].b;
            int bb = __float_as_int(rc.z);
            int ix0 = bb & 255, ix1 = (bb >> 8) & 255;
            int iy0 = (bb >> 16) & 255, iy1 = (bb >> 24) & 255;
            if (ix0 <= txm && ix1 >= tx0 && iy0 <= tym && iy1 >= ty0) {
                v0x = ra.x; v0y = ra.y; v1x = ra.z; v1y = ra.w;
                v2x = rc.x; v2y = rc.y;
                float e0x = __fsub_rn(v2x, v1x), e0y = __fsub_rn(v2y, v1y);
                float e1x = __fsub_rn(v0x, v2x), e1y = __fsub_rn(v0y, v2y);
                float e2x = __fsub_rn(v1x, v0x), e2y = __fsub_rn(v1y, v0y);
                // edge value at tile-corner pixel center; affine -> interval
                float w0 = (cx0 - v1x) * e0y - (cy0 - v1y) * e0x;
                float w1 = (cx0 - v2x) * e1y - (cy0 - v2y) * e1x;
                float w2 = (cx0 - v0x) * e2y - (cy0 - v0y) * e2x;
                float ax0 = EXT * e0y, ay0 = -EXT * e0x;
                float ax1 = EXT * e1y, ay1 = -EXT * e1x;
                float ax2 = EXT * e2y, ay2 = -EXT * e2x;
                float mn0 = w0 + fminf(ax0, 0.f) + fminf(ay0, 0.f);
                float mx0 = w0 + fmaxf(ax0, 0.f) + fmaxf(ay0, 0.f);
                float mn1 = w1 + fminf(ax1, 0.f) + fminf(ay1, 0.f);
                float mx1 = w1 + fmaxf(ax1, 0.f) + fmaxf(ay1, 0.f);
                float mn2 = w2 + fminf(ax2, 0.f) + fminf(ay2, 0.f);
                float mx2 = w2 + fmaxf(ax2, 0.f) + fmaxf(ay2, 0.f);
                bool posIn = fminf(mn0, fminf(mn1, mn2)) >  DELTA;
                bool negIn = fmaxf(mx0, fmaxf(mx1, mx2)) < -DELTA;
                if (posIn || negIn) cls = 2;
                else {
                    bool outz = (fminf(mx0, fminf(mx1, mx2)) < -DELTA) &&
                                (fmaxf(mn0, fmaxf(mn1, mn2)) >  DELTA);
                    if (!outz) cls = 1;
                }
            }
        }
        if (cls == 2) s_dom = 1;           // benign race: all writers store 1
        if (cls == 1) {
            int s = atomicAdd(&s_cnt, 1);  // LDS atomic; s < CAP by flush policy
            float* d = fl + s * 6;
            d[0] = v0x; d[1] = v0y; d[2] = v1x; d[3] = v1y; d[4] = v2x; d[5] = v2y;
        }
        __syncthreads();                   // (A) appends + dom flag visible
        int nowDom = s_dom, nowCnt = s_cnt;
        __syncthreads();                   // (B) reads done before next chunk writes
        if (nowDom) { covered = true; break; }        // uniform
        if (nowCnt >= CAP - 256) {                    // uniform; raster + reset
            for (int i = 0; i < nowCnt; ++i) {
                if (covered) break;
                const float* s6 = fl + i * 6;
                float a0x = s6[0], a0y = s6[1], a1x = s6[2], a1y = s6[3],
                      a2x = s6[4], a2y = s6[5];
                float e0x = __fsub_rn(a2x, a1x), e0y = __fsub_rn(a2y, a1y);
                float e1x = __fsub_rn(a0x, a2x), e1y = __fsub_rn(a0y, a2y);
                float e2x = __fsub_rn(a1x, a0x), e2y = __fsub_rn(a1y, a0y);
                float w0 = __fsub_rn(__fmul_rn(__fsub_rn(px, a1x), e0y),
                                     __fmul_rn(__fsub_rn(py, a1y), e0x));
                float w1 = __fsub_rn(__fmul_rn(__fsub_rn(px, a2x), e1y),
                                     __fmul_rn(__fsub_rn(py, a2y), e1x));
                float w2 = __fsub_rn(__fmul_rn(__fsub_rn(px, a0x), e2y),
                                     __fmul_rn(__fsub_rn(py, a0y), e2x));
                float mn = fminf(w0, fminf(w1, w2));
                float mx = fmaxf(w0, fmaxf(w1, w2));
                covered = covered || (mn >= 0.f) || (mx <= 0.f);
            }
            __syncthreads();
            if (tid == 0) s_cnt = 0;
            __syncthreads();
        }
    }
    if (!covered) {
        int n = s_cnt;   // visible: last appends precede a passed barrier
        for (int i = 0; i < n; ++i) {
            if (covered) break;
            const float* s6 = fl + i * 6;
            float a0x = s6[0], a0y = s6[1], a1x = s6[2], a1y = s6[3],
                  a2x = s6[4], a2y = s6[5];
            float e0x = __fsub_rn(a2x, a1x), e0y = __fsub_rn(a2y, a1y);
            float e1x = __fsub_rn(a0x, a2x), e1y = __fsub_rn(a0y, a2y);
            float e2x = __fsub_rn(a1x, a0x), e2y = __fsub_rn(a1y, a0y);
            float w0 = __fsub_rn(__fmul_rn(__fsub_rn(px, a1x), e0y),
                                 __fmul_rn(__fsub_rn(py, a1y), e0x));
            float w1 = __fsub_rn(__fmul_rn(__fsub_rn(px, a2x), e1y),
                                 __fmul_rn(__fsub_rn(py, a2y), e1x));
            float w2 = __fsub_rn(__fmul_rn(__fsub_rn(px, a0x), e2y),
                                 __fmul_rn(__fsub_rn(py, a0y), e2x));
            float mn = fminf(w0, fminf(w1, w2));
            float mx = fmaxf(w0, fmaxf(w1, w2));
            covered = covered || (mn >= 0.f) || (mx <= 0.f);
        }
    }
    out[((size_t)b << 16) + Y * IMG + X] = covered ? 1.0f : 0.0f;
}

// ---------------- Fallback path (proven) if workspace too small ----------------
__global__ void init_kernel(const float* __restrict__ verts,
                            const float* __restrict__ cams,
                            float4* __restrict__ out4, int n4,
                            float2* __restrict__ ndc, int BV, int V) {
    int i = blockIdx.x * blockDim.x + threadIdx.x;
    if (i < n4) out4[i] = make_float4(0.f, 0.f, 0.f, 0.f);
    if (i < BV) {
        int b = i / V;
        float f  = __fadd_rn(__fmul_rn(1.0f, cams[b * 3 + 0]), 0.0f);
        float cx = cams[b * 3 + 1];
        float cy = cams[b * 3 + 2];
        float image_size = __fmul_rn(cams[1], 2.0f);
        float x = verts[3 * i + 0];
        float y = verts[3 * i + 1];
        float z = __fadd_rn(verts[3 * i + 2], 0.0f);
        float px = __fadd_rn(__fdiv_rn(__fmul_rn(f, x), z), cx);
        float py = __fadd_rn(__fdiv_rn(__fmul_rn(f, y), z), cy);
        float nx = __fsub_rn(__fmul_rn(__fdiv_rn(px, image_size), 2.0f), 1.0f);
        float ny = __fsub_rn(__fmul_rn(__fdiv_rn(py, image_size), 2.0f), 1.0f);
        ndc[i] = make_float2(nx, ny);
    }
}

__global__ __launch_bounds__(256) void raster_kernel(
        const float2* __restrict__ ndc, const int* __restrict__ faces,
        float* __restrict__ out, int B, int V, int F) {
    int gid  = blockIdx.x * blockDim.x + threadIdx.x;
    int wave = gid >> 6;
    int lane = gid & 63;
    int widx = wave >> 2;
    int sub  = wave & (SPLIT - 1);
    if (widx >= B * F) return;
    int b  = widx / F;
    const int* fp = faces + (size_t)widx * 3;
    const float2* nb = ndc + (size_t)b * V;
    float2 v0 = nb[fp[0]];
    float2 v1 = nb[fp[1]];
    float2 v2 = nb[fp[2]];
    float area = __fsub_rn(
        __fmul_rn(__fsub_rn(v1.x, v0.x), __fsub_rn(v2.y, v0.y)),
        __fmul_rn(__fsub_rn(v1.y, v0.y), __fsub_rn(v2.x, v0.x)));
    if (!(fabsf(area) > 1e-12f)) return;
    float xmn = fminf(v0.x, fminf(v1.x, v2.x));
    float xmx = fmaxf(v0.x, fmaxf(v1.x, v2.x));
    float ymn = fminf(v0.y, fminf(v1.y, v2.y));
    float ymx = fmaxf(v0.y, fmaxf(v1.y, v2.y));
    int ix0 = max(0,       (int)floorf(xmn * 128.0f + 127.5f) - 1);
    int ix1 = min(IMG - 1, (int)ceilf (xmx * 128.0f + 127.5f) + 1);
    int iy0 = max(0,       (int)floorf(ymn * 128.0f + 127.5f) - 1);
    int iy1 = min(IMG - 1, (int)ceilf (ymx * 128.0f + 127.5f) + 1);
    if (ix1 < ix0 || iy1 < iy0) return;
    int W = ix1 - ix0 + 1, H = iy1 - iy0 + 1;
    int tws = 6, bestIt = ((W + 63) >> 6) * H;
    int it;
    it = ((W + 31) >> 5) * ((H + 1) >> 1); if (it < bestIt) { bestIt = it; tws = 5; }
    it = ((W + 15) >> 4) * ((H + 3) >> 2); if (it < bestIt) { bestIt = it; tws = 4; }
    it = ((W + 7)  >> 3) * ((H + 7) >> 3); if (it < bestIt) { bestIt = it; tws = 3; }
    int TW = 1 << tws, TH = 64 >> tws;
    int dx = lane & (TW - 1), dy = lane >> tws;
    float e0x = __fsub_rn(v2.x, v1.x), e0y = __fsub_rn(v2.y, v1.y);
    float e1x = __fsub_rn(v0.x, v2.x), e1y = __fsub_rn(v0.y, v2.y);
    float e2x = __fsub_rn(v1.x, v0.x), e2y = __fsub_rn(v1.y, v0.y);
    float* outb = out + (size_t)b * IMG * IMG;
    float pxStep = (float)TW * 0.0078125f;
    for (int ty = iy0 + sub * TH; ty <= iy1; ty += SPLIT * TH) {
        int y = ty + dy;
        bool yok = (y <= iy1);
        float py = (float)(2 * y + 1) * 0.00390625f - 1.0f;
        float t0 = __fmul_rn(__fsub_rn(py, v1.y), e0x);
        float t1 = __fmul_rn(__fsub_rn(py, v2.y), e1x);
        float t2 = __fmul_rn(__fsub_rn(py, v0.y), e2x);
        float* p = outb + y * IMG + ix0 + dx;
        int x = ix0 + dx;
        float px = (float)(2 * x + 1) * 0.00390625f - 1.0f;
        for (int tx = ix0; tx <= ix1; tx += TW) {
            float w0 = __fsub_rn(__fmul_rn(__fsub_rn(px, v1.x), e0y), t0);
            float w1 = __fsub_rn(__fmul_rn(__fsub_rn(px, v2.x), e1y), t1);
            float w2 = __fsub_rn(__fmul_rn(__fsub_rn(px, v0.x), e2y), t2);
            float mn = fminf(w0, fminf(w1, w2));
            float mx = fmaxf(w0, fmaxf(w1, w2));
            bool inside = (mn >= 0.f) | (mx <= 0.f);
            if (inside & yok & (x <= ix1)) *p = 1.0f;
            px += pxStep;
            x  += TW;
            p  += TW;
        }
    }
}

extern "C" void kernel_launch(void* const* d_in, const int* in_sizes, int n_in,
                              void* d_out, int out_size, void* d_ws, size_t ws_size,
                              hipStream_t stream) {
    const float* verts = (const float*)d_in[0];
    const int*   faces = (const int*)d_in[1];
    const float* cams  = (const float*)d_in[2];
    float* out = (float*)d_out;

    int B = in_sizes[2] / 3;
    int V = in_sizes[0] / (3 * B);
    int F = in_sizes[1] / (3 * B);

    size_t recsB = (size_t)B * F * sizeof(FaceRec);
    if (ws_size >= recsB) {
        FaceRec* recs = (FaceRec*)d_ws;
        int nf = B * F;
        hipLaunchKernelGGL(prep_kernel, dim3((nf + 255) / 256), dim3(256), 0,
                           stream, verts, faces, cams, recs, B, V, F);
        hipLaunchKernelGGL(tile_kernel, dim3(B << 8), dim3(256), 0,
                           stream, recs, out, B, F);
    } else {
        float2* ndc = (float2*)d_ws;
        int n4 = out_size / 4;
        int initThreads = n4 > B * V ? n4 : B * V;
        hipLaunchKernelGGL(init_kernel, dim3((initThreads + 255) / 256), dim3(256), 0,
                           stream, verts, cams, (float4*)d_out, n4, ndc, B * V, V);
        long long nthreads = (long long)B * F * SPLIT * 64;
        hipLaunchKernelGGL(raster_kernel, dim3((int)((nthreads + 255) / 256)),
                           dim3(256), 0, stream, ndc, faces, out, B, V, F);
    }
}